// Round 9
// baseline (164.361 us; speedup 1.0000x reference)
//
#include <hip/hip_runtime.h>
#include <math.h>

#define NP 128       // patches per side
#define NB 32        // batch (light dirs)

typedef float vf4 __attribute__((ext_vector_type(4)));  // native 16B vector

// ---------------------------------------------------------------------------
// One thread per (b, patch), b-major: tid = b*16384 + p (64 lanes cover 64
// consecutive patches -> contiguous 6KB spans per row). Structure proven to
// execute (round 7/8 landed stores). Inputs f32, OUTPUT f32 (402 MB).
// ---------------------------------------------------------------------------
__global__ void relight_simple(
    const float* __restrict__ ld,   // [32][2]
    const float* __restrict__ w1,   // [p][8][2]
    const float* __restrict__ b1,   // [p][8]
    const float* __restrict__ w2,   // [p][8][8]
    const float* __restrict__ b2,   // [p][8]
    const float* __restrict__ w3,   // [p][8][8]
    const float* __restrict__ b3,   // [p][8]
    const float* __restrict__ wo,   // [p][3][8]
    const float* __restrict__ bo,   // [p][3]
    float* __restrict__ out)        // [32][1024][1024][3] f32
{
    unsigned int tid = blockIdx.x * blockDim.x + threadIdx.x;  // 0 .. 524287
    int p = tid & 16383;         // patch id (consecutive within wave)
    int b = tid >> 14;           // light index
    int ph = p >> 7;             // patch row
    int pw = p & 127;            // patch col

    float x0 = ld[2 * b + 0];
    float x1 = ld[2 * b + 1];

    float h[8], g[8];

    {   // layer 1: 2 -> 8
        const float* W  = w1 + (size_t)p * 16;
        const float* Bv = b1 + (size_t)p * 8;
#pragma unroll
        for (int o = 0; o < 8; ++o) {
            float s = fmaf(W[2 * o + 0], x0, fmaf(W[2 * o + 1], x1, Bv[o]));
            h[o] = fmaxf(0.f, s);
        }
    }
    {   // layer 2: 8 -> 8
        const float* W  = w2 + (size_t)p * 64;
        const float* Bv = b2 + (size_t)p * 8;
#pragma unroll
        for (int o = 0; o < 8; ++o) {
            float s = Bv[o];
#pragma unroll
            for (int i = 0; i < 8; ++i) s = fmaf(W[8 * o + i], h[i], s);
            g[o] = fmaxf(0.f, s);
        }
    }
    {   // layer 3: 8 -> 8
        const float* W  = w3 + (size_t)p * 64;
        const float* Bv = b3 + (size_t)p * 8;
#pragma unroll
        for (int o = 0; o < 8; ++o) {
            float s = Bv[o];
#pragma unroll
            for (int i = 0; i < 8; ++i) s = fmaf(W[8 * o + i], g[i], s);
            h[o] = fmaxf(0.f, s);
        }
    }

    float c0, c1, c2;
    {   // out layer: 8 -> 3, sigmoid
        const float* W  = wo + (size_t)p * 24;
        const float* Bv = bo + (size_t)p * 3;
        float c[3];
#pragma unroll
        for (int cc = 0; cc < 3; ++cc) {
            float s = Bv[cc];
#pragma unroll
            for (int i = 0; i < 8; ++i) s = fmaf(W[8 * cc + i], h[i], s);
            c[cc] = 1.f / (1.f + expf(-s));
        }
        c0 = c[0]; c1 = c[1]; c2 = c[2];
    }

    // One patch row = 8 px * 3 ch = 24 f32 = 6 float4 chunks; chunk j starts
    // at channel (4j)%3, pattern repeats with period 3.
    vf4 v0, v1, v2;
    v0.x = c0; v0.y = c1; v0.z = c2; v0.w = c0;   // j%3==0
    v1.x = c1; v1.y = c2; v1.z = c0; v1.w = c1;   // j%3==1
    v2.x = c2; v2.y = c0; v2.z = c1; v2.w = c2;   // j%3==2

    // float index base: b*1024*1024*3 + ph*8*1024*3 + pw*8*3 ; /4 for vf4
    vf4* op = (vf4*)out + ((size_t)b * 3145728 + (size_t)ph * 8 * 3072
                           + (size_t)pw * 24) / 4;
#pragma unroll
    for (int r = 0; r < 8; ++r) {
        vf4* rp = op + (size_t)r * 768;   // 3072 floats / 4
        rp[0] = v0; rp[1] = v1; rp[2] = v2;
        rp[3] = v0; rp[4] = v1; rp[5] = v2;
    }
}

extern "C" void kernel_launch(void* const* d_in, const int* in_sizes, int n_in,
                              void* d_out, int out_size, void* d_ws, size_t ws_size,
                              hipStream_t stream) {
    const float* ld = (const float*)d_in[0];
    const float* w1 = (const float*)d_in[1];
    const float* b1 = (const float*)d_in[2];
    const float* w2 = (const float*)d_in[3];
    const float* b2 = (const float*)d_in[4];
    const float* w3 = (const float*)d_in[5];
    const float* b3 = (const float*)d_in[6];
    const float* wo = (const float*)d_in[7];
    const float* bo = (const float*)d_in[8];

    float* out = (float*)d_out;

    relight_simple<<<dim3((NB * NP * NP) / 256), dim3(256), 0, stream>>>(
        ld, w1, b1, w2, b2, w3, b3, wo, bo, out);
}

// Round 10
// 95.790 us; speedup vs baseline: 1.7159x; 1.7159x over previous
//
#include <hip/hip_runtime.h>
#include <math.h>

#define NP 128       // patches per side
#define NB 32        // batch (light dirs)

typedef float vf4 __attribute__((ext_vector_type(4)));  // native 16B vector

// ---------------------------------------------------------------------------
// Fused, coalesced: one block (256 thr) per (ph, b).
//  phase 1: threads 0..127 run the 2->8->8->8->3 MLP for patch (ph, t),
//           write 3 f32 colors to LDS.
//  phase 2: all 256 threads write the 8x1024x3 f32 block as 6144 float4
//           chunks, 24/thread, consecutive lanes -> consecutive chunks
//           (wave-contiguous 1KB per store instruction), non-temporal.
// bid = ph*32 + b: 32 consecutive blocks share one row's weights (L2 reuse).
// ---------------------------------------------------------------------------
__global__ __launch_bounds__(256) void fused_relight(
    const float* __restrict__ ld,   // [32][2]
    const float* __restrict__ w1,   // [p][8][2]
    const float* __restrict__ b1,   // [p][8]
    const float* __restrict__ w2,   // [p][8][8]
    const float* __restrict__ b2,   // [p][8]
    const float* __restrict__ w3,   // [p][8][8]
    const float* __restrict__ b3,   // [p][8]
    const float* __restrict__ wo,   // [p][3][8]
    const float* __restrict__ bo,   // [p][3]
    float* __restrict__ out)        // [32][1024][1024][3] f32
{
    int bid = blockIdx.x;        // 0 .. 4095
    int ph = bid >> 5;           // patch row
    int b  = bid & 31;           // light index
    int t  = threadIdx.x;        // 0 .. 255

    __shared__ float cl[NP * 3];  // 384 floats

    if (t < NP) {
        int p = ph * NP + t;     // patch id
        float x0 = ld[2 * b + 0];
        float x1 = ld[2 * b + 1];

        float h[8], g[8];
        {   // layer 1: 2 -> 8
            const float* W  = w1 + (size_t)p * 16;
            const float* Bv = b1 + (size_t)p * 8;
#pragma unroll
            for (int o = 0; o < 8; ++o) {
                float s = fmaf(W[2 * o + 0], x0, fmaf(W[2 * o + 1], x1, Bv[o]));
                h[o] = fmaxf(0.f, s);
            }
        }
        {   // layer 2: 8 -> 8
            const float* W  = w2 + (size_t)p * 64;
            const float* Bv = b2 + (size_t)p * 8;
#pragma unroll
            for (int o = 0; o < 8; ++o) {
                float s = Bv[o];
#pragma unroll
                for (int i = 0; i < 8; ++i) s = fmaf(W[8 * o + i], h[i], s);
                g[o] = fmaxf(0.f, s);
            }
        }
        {   // layer 3: 8 -> 8
            const float* W  = w3 + (size_t)p * 64;
            const float* Bv = b3 + (size_t)p * 8;
#pragma unroll
            for (int o = 0; o < 8; ++o) {
                float s = Bv[o];
#pragma unroll
                for (int i = 0; i < 8; ++i) s = fmaf(W[8 * o + i], g[i], s);
                h[o] = fmaxf(0.f, s);
            }
        }
        {   // out layer: 8 -> 3, sigmoid -> LDS
            const float* W  = wo + (size_t)p * 24;
            const float* Bv = bo + (size_t)p * 3;
#pragma unroll
            for (int c = 0; c < 3; ++c) {
                float s = Bv[c];
#pragma unroll
                for (int i = 0; i < 8; ++i) s = fmaf(W[8 * c + i], h[i], s);
                cl[t * 3 + c] = 1.f / (1.f + expf(-s));
            }
        }
    }
    __syncthreads();

    // Phase 2: 8 rows * 3072 floats = 6144 float4 chunks. Chunk ct within a
    // row covers floats 4ct..4ct+3: patch pw = ct/6, start channel s = ct%3
    // (4 ≡ 1 mod 3), values [s, s+1, s+2, s] mod 3.
    vf4* op = (vf4*)out + (size_t)b * 786432 + (size_t)ph * 6144;

#pragma unroll
    for (int k = 0; k < 24; ++k) {
        int c  = k * 256 + t;         // 0 .. 6143
        int row = c / 768;            // 0..7 (identical data each row)
        int ct = c - row * 768;       // 0..767
        int pw = ct / 6;              // patch col
        int s  = ct % 3;              // first channel in this chunk

        float c0 = cl[pw * 3 + 0];
        float c1 = cl[pw * 3 + 1];
        float c2 = cl[pw * 3 + 2];
        float ca = (s == 0) ? c0 : ((s == 1) ? c1 : c2);
        float cb = (s == 0) ? c1 : ((s == 1) ? c2 : c0);
        float cc = (s == 0) ? c2 : ((s == 1) ? c0 : c1);

        vf4 v;
        v.x = ca; v.y = cb; v.z = cc; v.w = ca;
        __builtin_nontemporal_store(v, &op[c]);
    }
}

extern "C" void kernel_launch(void* const* d_in, const int* in_sizes, int n_in,
                              void* d_out, int out_size, void* d_ws, size_t ws_size,
                              hipStream_t stream) {
    const float* ld = (const float*)d_in[0];
    const float* w1 = (const float*)d_in[1];
    const float* b1 = (const float*)d_in[2];
    const float* w2 = (const float*)d_in[3];
    const float* b2 = (const float*)d_in[4];
    const float* w3 = (const float*)d_in[5];
    const float* b3 = (const float*)d_in[6];
    const float* wo = (const float*)d_in[7];
    const float* bo = (const float*)d_in[8];

    float* out = (float*)d_out;

    fused_relight<<<dim3(NP * NB), dim3(256), 0, stream>>>(
        ld, w1, b1, w2, b2, w3, b3, wo, bo, out);
}